// Round 17
// baseline (1236.998 us; speedup 1.0000x reference)
//
#include <hip/hip_runtime.h>

#define DEPTH 6
#define DIM 512
#define HEADS 8
#define DHEAD 64
#define MLP_D 2048
#define SEQ 760
#define SEQP 768
#define BATCH 16
#define ROWS (BATCH * SEQ)      // 12160 = 95 * 128
#define QK_SCALE 0.125f
#define C2LOG (QK_SCALE * 1.44269504089f)   // fold softmax into base-2

typedef float f32x4 __attribute__((ext_vector_type(4)));
typedef __bf16 bf16x8 __attribute__((ext_vector_type(8)));

__device__ inline f32x4 mfma16(bf16x8 a, bf16x8 b, f32x4 c) {
  return __builtin_amdgcn_mfma_f32_16x16x32_bf16(a, b, c, 0, 0, 0);
}

#define GLOAD_LDS(gp, lp) \
  __builtin_amdgcn_global_load_lds( \
      (const __attribute__((address_space(1))) void*)(gp), \
      (__attribute__((address_space(3))) void*)(lp), 16, 0, 0)

// bijective XCD-chunk remap (m204): consecutive remapped ids share an XCD
__device__ inline int swz_flat(int flat, int total) {
  int xcd = flat & 7, idx = flat >> 3;
  int q = total >> 3, r = total & 7;
  return (xcd < r ? xcd * (q + 1) : r * (q + 1) + (xcd - r) * q) + idx;
}

// ---------------- valid-key scan: didx[b][j] = compacted pos or -1; vcnt[b] ----------------
__global__ __launch_bounds__(64) void scan_kernel(
    const int* __restrict__ vseq, int* __restrict__ didx, int* __restrict__ vcnt)
{
  int b = blockIdx.x;
  if (threadIdx.x == 0) {
    int c = 0;
    for (int j = 0; j < SEQ; ++j) {
      bool valid = (j == 0) || (vseq[b * (SEQ - 1) + j - 1] != 0);
      didx[b * SEQ + j] = valid ? c : -1;
      if (valid) ++c;
    }
    vcnt[b] = c;
  }
}

// ---------------- LayerNorm: fp32 in -> bf16 out (one wave per row) ----------------
__global__ __launch_bounds__(256) void ln_kernel(
    const float* __restrict__ x, const float* __restrict__ gw,
    const float* __restrict__ bw, __bf16* __restrict__ out)
{
  int wave = threadIdx.x >> 6, lane = threadIdx.x & 63;
  int row = blockIdx.x * 4 + wave;
  const float4* xr = (const float4*)(x + (size_t)row * DIM);
  float4 a = xr[lane * 2], b = xr[lane * 2 + 1];
  float s  = a.x + a.y + a.z + a.w + b.x + b.y + b.z + b.w;
  float ss = a.x*a.x + a.y*a.y + a.z*a.z + a.w*a.w
           + b.x*b.x + b.y*b.y + b.z*b.z + b.w*b.w;
  #pragma unroll
  for (int m = 1; m < 64; m <<= 1) {
    s  += __shfl_xor(s, m);
    ss += __shfl_xor(ss, m);
  }
  float mu  = s * (1.0f / DIM);
  float var = ss * (1.0f / DIM) - mu * mu;
  float rs  = rsqrtf(var + 1e-5f);
  const float4* gr = (const float4*)gw;
  const float4* br = (const float4*)bw;
  float4 g0 = gr[lane * 2], g1 = gr[lane * 2 + 1];
  float4 b0 = br[lane * 2], b1 = br[lane * 2 + 1];
  bf16x8 o;
  o[0] = (__bf16)((a.x - mu) * rs * g0.x + b0.x);
  o[1] = (__bf16)((a.y - mu) * rs * g0.y + b0.y);
  o[2] = (__bf16)((a.z - mu) * rs * g0.z + b0.z);
  o[3] = (__bf16)((a.w - mu) * rs * g0.w + b0.w);
  o[4] = (__bf16)((b.x - mu) * rs * g1.x + b1.x);
  o[5] = (__bf16)((b.y - mu) * rs * g1.y + b1.y);
  o[6] = (__bf16)((b.z - mu) * rs * g1.z + b1.z);
  o[7] = (__bf16)((b.w - mu) * rs * g1.w + b1.w);
  *(bf16x8*)(out + (size_t)row * DIM + lane * 8) = o;
}

// ---------------- fused weight conversion: all 4 weights of one layer ----------------
__global__ __launch_bounds__(256) void wconv_all_kernel(
    const float* __restrict__ wqkv, const float* __restrict__ wout,
    const float* __restrict__ w1, const float* __restrict__ w2,
    __bf16* __restrict__ tq, __bf16* __restrict__ to,
    __bf16* __restrict__ t1, __bf16* __restrict__ t2)
{
  __shared__ float tile[32][33];
  int id = blockIdx.x;
  const float* W; __bf16* Wt; int K, N, nx, rel;
  if (id < 768)       { W = wqkv; Wt = tq; K = 512;  N = 1536; nx = 48; rel = id; }
  else if (id < 1024) { W = wout; Wt = to; K = 512;  N = 512;  nx = 16; rel = id - 768; }
  else if (id < 2048) { W = w1;   Wt = t1; K = 512;  N = 2048; nx = 64; rel = id - 1024; }
  else                { W = w2;   Wt = t2; K = 2048; N = 512;  nx = 16; rel = id - 2048; }
  int n0 = (rel % nx) * 32, k0 = (rel / nx) * 32;
  int tx = threadIdx.x, ty = threadIdx.y;
  #pragma unroll
  for (int r = ty; r < 32; r += 8)
    tile[r][tx] = W[(size_t)(k0 + r) * N + n0 + tx];
  __syncthreads();
  #pragma unroll
  for (int r = ty; r < 32; r += 8)
    Wt[(size_t)(n0 + r) * K + k0 + tx] = (__bf16)tile[tx][r];
}

// ---------------- GEMM: C[M,N] = A[M,K](bf16) * Bt[N,K]^T (bf16) ----------------
// R10/R13/R15-verified schedule (BEST): 512 threads, 8 waves (4r x 2c, 32x64
// wave tiles), 128x128 tile, BK=64, DOUBLE-buffered (2 x 32KB -- triple does
// NOT fit: 3 x 32KB = 96KB -> 1 block/CU, R16 errata), counted vmcnt(4),
// two barriers per K-step, STAGE(t+2) after barrier#2.  T2 both-sides XOR
// swizzle (conflicts 73x down).
// mode 3 scatters K rows / V^T cols to COMPACTED key positions via didx.
#define CS_LD 136   // bf16 bounce stride (elems)
#define CF_LD 132   // f32 bounce stride (elems)
__global__ __launch_bounds__(512, 4) void gemm_kernel(
    const __bf16* __restrict__ A, const __bf16* __restrict__ Bt,
    int M, int N, int K, int mode,
    float* Cf, __bf16* __restrict__ Cb,
    const float* __restrict__ bias, const float* resid,
    __bf16* __restrict__ qo, __bf16* __restrict__ ko, __bf16* __restrict__ vto,
    const int* __restrict__ didx)
{
  __shared__ __align__(16) __bf16 SS[32768];  // 64KB: 2x(A+B) staging; epilogue bounce aliased
  __bf16* A0 = SS;
  __bf16* B0 = SS + 8192;
  __bf16* A1 = SS + 16384;
  __bf16* B1 = SS + 24576;
  int tid = threadIdx.x;
  int lane = tid & 63;
  int wave = tid >> 6;          // 0..7
  int wr = wave >> 1;           // 0..3 : 32-row band
  int wc = wave & 1;            // 0..1 : 64-col band

  int wg = swz_flat(blockIdx.y * gridDim.x + blockIdx.x, gridDim.x * gridDim.y);
  int jblk = wg % gridDim.x;
  int iblk = wg / gridDim.x;

  const __bf16* Ab = A  + (size_t)(iblk * 128) * K;
  const __bf16* Bb = Bt + (size_t)(jblk * 128) * K;
  int srow = tid >> 3;          // 0..63
  // T2: source chunk swizzled so LDS chunk c at row r holds global chunk c^(r&7)
  int scolsw = (((tid & 7) ^ (srow & 7)) * 8);
  f32x4 acc[2][4] = {};

  #define STAGE(k0, Ad, Bd) { \
    _Pragma("unroll") \
    for (int c = 0; c < 2; ++c) { \
      int row = c * 64 + srow; \
      GLOAD_LDS(Ab + (size_t)row * K + (k0) + scolsw, (Ad) + c * 4096 + tid * 8); \
      GLOAD_LDS(Bb + (size_t)row * K + (k0) + scolsw, (Bd) + c * 4096 + tid * 8); \
    } }

  #define COMPUTE(As, Bs) { \
    _Pragma("unroll") \
    for (int kk = 0; kk < 2; ++kk) { \
      int ch = ((kk * 4 + (lane >> 4)) ^ (lane & 7)) * 8; \
      bf16x8 af[2], bfr[4]; \
      _Pragma("unroll") \
      for (int mi = 0; mi < 2; ++mi) \
        af[mi] = *(const bf16x8*)((As) + (wr * 32 + mi * 16 + (lane & 15)) * 64 + ch); \
      _Pragma("unroll") \
      for (int ni = 0; ni < 4; ++ni) \
        bfr[ni] = *(const bf16x8*)((Bs) + (wc * 64 + ni * 16 + (lane & 15)) * 64 + ch); \
      _Pragma("unroll") \
      for (int mi = 0; mi < 2; ++mi) \
        _Pragma("unroll") \
        for (int ni = 0; ni < 4; ++ni) \
          acc[mi][ni] = mfma16(af[mi], bfr[ni], acc[mi][ni]); \
    } }

  int nst = K >> 6;             // >= 8 for all our shapes
  STAGE(0, A0, B0);
  STAGE(64, A1, B1);            // 8 loads in flight
  for (int t = 0; t < nst - 1; ++t) {
    const __bf16* As = (t & 1) ? A1 : A0;
    const __bf16* Bs = (t & 1) ? B1 : B0;
    asm volatile("s_waitcnt vmcnt(4)" ::: "memory");  // tile t landed (own loads)
    __builtin_amdgcn_s_barrier();                      // all waves' tile t landed
    __builtin_amdgcn_sched_barrier(0);
    COMPUTE(As, Bs);
    __builtin_amdgcn_s_barrier();                      // all waves done reading buf t
    if (t + 2 < nst)
      STAGE((t + 2) << 6, (__bf16*)As, (__bf16*)Bs);   // refill the buffer just consumed
  }
  asm volatile("s_waitcnt vmcnt(0)" ::: "memory");
  __builtin_amdgcn_s_barrier();
  __builtin_amdgcn_sched_barrier(0);
  {
    const __bf16* As = ((nst - 1) & 1) ? A1 : A0;
    const __bf16* Bs = ((nst - 1) & 1) ? B1 : B0;
    COMPUTE(As, Bs);
  }
  __syncthreads();   // protect SS reuse by epilogue bounce

  if (mode == 2) {
    float* Csf = (float*)SS;   // 64 x CF_LD half-tile
    #pragma unroll
    for (int h = 0; h < 2; ++h) {
      if (h) __syncthreads();
      if ((wr >> 1) == h) {
        #pragma unroll
        for (int mi = 0; mi < 2; ++mi)
          #pragma unroll
          for (int ni = 0; ni < 4; ++ni) {
            int lr = (wr & 1) * 32 + mi * 16 + (lane >> 4) * 4;
            int lc = wc * 64 + ni * 16 + (lane & 15);
            #pragma unroll
            for (int e = 0; e < 4; ++e)
              Csf[(lr + e) * CF_LD + lc] = acc[mi][ni][e];
          }
      }
      __syncthreads();
      #pragma unroll
      for (int c = 0; c < 4; ++c) {
        int elem = c * 2048 + tid * 4;
        int row = elem >> 7, col = elem & 127;
        float4 v = *(float4*)(Csf + row * CF_LD + col);
        int gi = iblk * 128 + h * 64 + row;
        int gj = jblk * 128 + col;
        float4 bz = *(const float4*)(bias + gj);
        float4 rz = *(const float4*)(resid + (size_t)gi * N + gj);
        v.x += bz.x + rz.x; v.y += bz.y + rz.y;
        v.z += bz.z + rz.z; v.w += bz.w + rz.w;
        *(float4*)(Cf + (size_t)gi * N + gj) = v;
      }
    }
    return;
  }

  if (mode == 3 && jblk >= 8) {
    // V^T: scatter each element to compacted key column didx[n] (2B predicated stores)
    #pragma unroll
    for (int mi = 0; mi < 2; ++mi) {
      int i0 = iblk * 128 + wr * 32 + mi * 16 + (lane >> 4) * 4;
      int b = i0 / SEQ;                // i0%4==0 and SEQ%4==0 -> same b for 4 e's
      int n0 = i0 - b * SEQ;
      int dn[4];
      #pragma unroll
      for (int e = 0; e < 4; ++e) dn[e] = didx[b * SEQ + n0 + e];  // hoisted
      #pragma unroll
      for (int ni = 0; ni < 4; ++ni) {
        int j = (jblk - 8) * 128 + wc * 64 + ni * 16 + (lane & 15);  // 0..511
        int hh = j >> 6, d = j & 63;
        __bf16* vbase = vto + ((size_t)(b * HEADS + hh) * DHEAD + d) * SEQP;
        #pragma unroll
        for (int e = 0; e < 4; ++e)
          if (dn[e] >= 0) vbase[dn[e]] = (__bf16)acc[mi][ni][e];
      }
    }
    return;
  }

  // bf16 bounce: modes 0, 1, 3(q/k)
  __bf16* Cs = SS;
  #pragma unroll
  for (int mi = 0; mi < 2; ++mi)
    #pragma unroll
    for (int ni = 0; ni < 4; ++ni) {
      int lr = wr * 32 + mi * 16 + (lane >> 4) * 4;
      int lc = wc * 64 + ni * 16 + (lane & 15);
      #pragma unroll
      for (int e = 0; e < 4; ++e) {
        float v = acc[mi][ni][e];
        if (mode == 1) {
          v += bias[jblk * 128 + lc];
          v = 0.5f * v * (1.0f + erff(v * 0.70710678118654752f));
        }
        Cs[(lr + e) * CS_LD + lc] = (__bf16)v;
      }
    }
  __syncthreads();
  #pragma unroll
  for (int c = 0; c < 4; ++c) {
    int elem = c * 4096 + tid * 8;
    int row = elem >> 7, col = elem & 127;
    bf16x8 v = *(bf16x8*)(Cs + row * CS_LD + col);
    int gi = iblk * 128 + row;
    if (mode <= 1) {
      *(bf16x8*)(Cb + (size_t)gi * N + jblk * 128 + col) = v;
    } else {
      int b = gi / SEQ;
      int n = gi - b * SEQ;
      int j = jblk * 128 + col;
      int hh = (j >> 6) & 7, d = j & 63;
      size_t bh = (size_t)(b * HEADS + hh);
      if (jblk < 4) {
        *(bf16x8*)(qo + (bh * SEQ + n) * DHEAD + d) = v;
      } else {
        int dn = didx[b * SEQ + n];
        if (dn >= 0) *(bf16x8*)(ko + (bh * SEQP + dn) * DHEAD + d) = v;
      }
    }
  }
}

// ---------------- Flash attention over COMPACTED keys ----------------
// R13-verified: 8 waves x 16 q-rows; global_load_lds staging (linear [64][64]
// LDS, T2 both-sides XOR swizzle), double-buffered counted vmcnt(2).
#define KVB 64
#define PS_LD 68
__global__ __launch_bounds__(512, 3) void attn_kernel(
    const __bf16* __restrict__ qb, const __bf16* __restrict__ kb,
    const __bf16* __restrict__ vtb, const int* __restrict__ vcnt,
    __bf16* __restrict__ ob)
{
  __shared__ __align__(16) __bf16 KV[4 * KVB * DHEAD];   // K0,V0,K1,V1 : 32KB linear
  __shared__ __align__(16) __bf16 Ps[8][16 * PS_LD];     // per-wave P bounce
  __bf16* K0 = KV;
  __bf16* V0 = KV + 4096;
  __bf16* K1 = KV + 8192;
  __bf16* V1 = KV + 12288;
  int tid = threadIdx.x, lane = tid & 63, wave = tid >> 6;

  int wg = swz_flat(blockIdx.y * gridDim.x + blockIdx.x, gridDim.x * gridDim.y);
  int qblk = wg % gridDim.x;       // 0..5
  int bh   = wg / gridDim.x;       // 0..127
  int b = bh >> 3, hh = bh & 7;
  int q0 = qblk * 128 + wave * 16;

  int vc = vcnt[b];
  int nt = (vc + KVB - 1) >> 6;    // >=1 (key 0 always valid)

  const __bf16* qbase = qb  + (size_t)bh * SEQ * DHEAD;
  const __bf16* kbase = kb  + (size_t)bh * SEQP * DHEAD;
  const __bf16* vbase = vtb + (size_t)bh * DHEAD * SEQP;

  int qrow = q0 + (lane & 15);
  if (qrow > SEQ - 1) qrow = SEQ - 1;
  bf16x8 qf[2];
  #pragma unroll
  for (int ks = 0; ks < 2; ++ks)
    qf[ks] = *(const bf16x8*)(qbase + (size_t)qrow * DHEAD + ks * 32 + (lane >> 4) * 8);

  f32x4 oacc[4] = {};
  float mi[4] = {-INFINITY, -INFINITY, -INFINITY, -INFINITY};
  float li[4] = {0.f, 0.f, 0.f, 0.f};   // per-lane partial, reduced once at end

  // drain q loads so manual vmcnt counting below sees only gload_lds ops
  asm volatile("s_waitcnt vmcnt(0)" ::: "memory");

  // staging geometry: thread -> (row = tid>>3, chunk = tid&7); LDS dest linear
  // tid*16B; source chunk pre-swizzled by (row&7) so LDS[r][c] = global[r][c^(r&7)].
  // buffers are SEQP=768 wide -> all tile loads in-bounds; tail keys masked.
  int srow = tid >> 3;
  int schx = ((tid & 7) ^ (srow & 7)) * 8;

  #define ASTAGE(kt, Kd, Vd) { \
    GLOAD_LDS(kbase + (size_t)((kt) * KVB + srow) * DHEAD + schx, (Kd) + tid * 8); \
    GLOAD_LDS(vbase + (size_t)srow * SEQP + (kt) * KVB + schx, (Vd) + tid * 8); }

  ASTAGE(0, K0, V0);
  if (nt > 1) ASTAGE(1, K1, V1);

  for (int kt = 0; kt < nt; ++kt) {
    const __bf16* Ks = (kt & 1) ? K1 : K0;
    const __bf16* Vs = (kt & 1) ? V1 : V0;
    if (kt + 1 < nt) { asm volatile("s_waitcnt vmcnt(2)" ::: "memory"); }
    else             { asm volatile("s_waitcnt vmcnt(0)" ::: "memory"); }
    __builtin_amdgcn_s_barrier();           // all waves' tile kt landed
    __builtin_amdgcn_sched_barrier(0);

    float addf[4];
    #pragma unroll
    for (int sj = 0; sj < 4; ++sj)
      addf[sj] = (kt * KVB + sj * 16 + (lane & 15) < vc) ? 0.0f : -1e9f;

    f32x4 s[4] = {};
    __builtin_amdgcn_s_setprio(1);
    #pragma unroll
    for (int ks = 0; ks < 2; ++ks) {
      int ch = ((ks * 4 + (lane >> 4)) ^ (lane & 7)) * 8;
      #pragma unroll
      for (int sj = 0; sj < 4; ++sj) {
        bf16x8 kf = *(const bf16x8*)(Ks + (sj * 16 + (lane & 15)) * DHEAD + ch);
        s[sj] = mfma16(qf[ks], kf, s[sj]);
      }
    }
    __builtin_amdgcn_s_setprio(0);
    #pragma unroll
    for (int sj = 0; sj < 4; ++sj)
      #pragma unroll
      for (int e = 0; e < 4; ++e)
        s[sj][e] = fmaf(s[sj][e], C2LOG, addf[sj]);

    float vmax[4];
    #pragma unroll
    for (int e = 0; e < 4; ++e) {
      float v = fmaxf(fmaxf(s[0][e], s[1][e]), fmaxf(s[2][e], s[3][e]));
      v = fmaxf(v, __shfl_xor(v, 1));
      v = fmaxf(v, __shfl_xor(v, 2));
      v = fmaxf(v, __shfl_xor(v, 4));
      v = fmaxf(v, __shfl_xor(v, 8));
      vmax[e] = v;
    }
    // defer-max: only rescale when some row grew past mi + 11 (2^11 P-headroom)
    bool need = false;
    #pragma unroll
    for (int e = 0; e < 4; ++e) need |= (vmax[e] > mi[e] + 11.0f);
    if (__any(need)) {
      #pragma unroll
      for (int e = 0; e < 4; ++e) {
        float mnew = fmaxf(mi[e], vmax[e]);
        float alpha = exp2f(mi[e] - mnew);
        mi[e] = mnew;
        li[e] *= alpha;
        #pragma unroll
        for (int dj = 0; dj < 4; ++dj)
          oacc[dj][e] *= alpha;
      }
    }
    #pragma unroll
    for (int e = 0; e < 4; ++e) {
      float sum = 0.f;
      #pragma unroll
      for (int sj = 0; sj < 4; ++sj) {
        float p = exp2f(s[sj][e] - mi[e]);
        s[sj][e] = p;
        sum += p;
      }
      li[e] += sum;
    }

    // P (D-layout) -> per-wave LDS -> A-layout fragments
    #pragma unroll
    for (int sj = 0; sj < 4; ++sj)
      #pragma unroll
      for (int e = 0; e < 4; ++e)
        Ps[wave][((lane >> 4) * 4 + e) * PS_LD + sj * 16 + (lane & 15)] = (__bf16)s[sj][e];
    bf16x8 pf[2];
    #pragma unroll
    for (int c = 0; c < 2; ++c)
      pf[c] = *(const bf16x8*)(&Ps[wave][(lane & 15) * PS_LD + c * 32 + (lane >> 4) * 8]);
    __builtin_amdgcn_s_setprio(1);
    #pragma unroll
    for (int dj = 0; dj < 4; ++dj) {
      #pragma unroll
      for (int c = 0; c < 2; ++c) {
        int ch = ((c * 4 + (lane >> 4)) ^ (lane & 7)) * 8;
        bf16x8 vf = *(const bf16x8*)(Vs + (dj * 16 + (lane & 15)) * DHEAD + ch);
        oacc[dj] = mfma16(pf[c], vf, oacc[dj]);
      }
    }
    __builtin_amdgcn_s_setprio(0);

    __builtin_amdgcn_s_barrier();           // all waves done reading buffers kt
    if (kt + 2 < nt) {
      __bf16* Kn = (kt & 1) ? K1 : K0;      // buffer (kt+2)&1 = just-consumed one
      __bf16* Vn = (kt & 1) ? V1 : V0;
      ASTAGE(kt + 2, Kn, Vn);
    }
  }

  // final cross-lane l reduction (once, instead of per tile)
  #pragma unroll
  for (int e = 0; e < 4; ++e) {
    float l = li[e];
    l += __shfl_xor(l, 1);
    l += __shfl_xor(l, 2);
    l += __shfl_xor(l, 4);
    l += __shfl_xor(l, 8);
    li[e] = l;
  }

  #pragma unroll
  for (int e = 0; e < 4; ++e) {
    int n = q0 + (lane >> 4) * 4 + e;
    if (n < SEQ) {
      float inv = 1.0f / li[e];
      #pragma unroll
      for (int dj = 0; dj < 4; ++dj)
        ob[((size_t)b * SEQ + n) * DIM + hh * DHEAD + dj * 16 + (lane & 15)] =
            (__bf16)(oacc[dj][e] * inv);
    }
  }
}

// ---------------- workspace layout (bytes) ----------------
static const size_t OFF_WTQKV = 0;                               // 1536*512*2
static const size_t OFF_WTOUT = 1572864;                         // 512*512*2
static const size_t OFF_WTW1  = OFF_WTOUT + 524288;              // 2048*512*2
static const size_t OFF_WTW2  = OFF_WTW1 + 2097152;              // 512*2048*2
static const size_t OFF_H     = OFF_WTW2 + 2097152;              // 12160*512*2
static const size_t OFF_Q     = OFF_H  + 12451840;               // 128*760*64*2
static const size_t OFF_K     = OFF_Q  + 12451840;               // 128*768*64*2
static const size_t OFF_VT    = OFF_K  + 12582912;               // 128*64*768*2
static const size_t OFF_O     = OFF_VT + 12582912;               // 12160*512*2
static const size_t OFF_IDX   = OFF_O  + 12451840;               // 16*760*4
static const size_t OFF_VC    = OFF_IDX + 49152;                 // 16*4
static const size_t OFF_FF    = OFF_Q;  // ff aliases q/k/vt/o (dead by then)

extern "C" void kernel_launch(void* const* d_in, const int* in_sizes, int n_in,
                              void* d_out, int out_size, void* d_ws, size_t ws_size,
                              hipStream_t stream) {
  const float* x    = (const float*)d_in[0];
  const int*   vseq = (const int*)d_in[1];
  const float* ln1g = (const float*)d_in[3];
  const float* ln1b = (const float*)d_in[4];
  const float* wqkv = (const float*)d_in[5];
  const float* wout = (const float*)d_in[6];
  const float* bout = (const float*)d_in[7];
  const float* ln2g = (const float*)d_in[8];
  const float* ln2b = (const float*)d_in[9];
  const float* w1   = (const float*)d_in[10];
  const float* b1   = (const float*)d_in[11];
  const float* w2   = (const float*)d_in[12];
  const float* b2   = (const float*)d_in[13];

  float* xbuf = (float*)d_out;
  char* ws = (char*)d_ws;
  __bf16* wt_qkv = (__bf16*)(ws + OFF_WTQKV);
  __bf16* wt_out = (__bf16*)(ws + OFF_WTOUT);
  __bf16* wt_w1  = (__bf16*)(ws + OFF_WTW1);
  __bf16* wt_w2  = (__bf16*)(ws + OFF_WTW2);
  __bf16* hb     = (__bf16*)(ws + OFF_H);
  __bf16* qbuf   = (__bf16*)(ws + OFF_Q);
  __bf16* kbuf   = (__bf16*)(ws + OFF_K);
  __bf16* vtbuf  = (__bf16*)(ws + OFF_VT);
  __bf16* obuf   = (__bf16*)(ws + OFF_O);
  __bf16* ffbuf  = (__bf16*)(ws + OFF_FF);
  int* didx = (int*)(ws + OFF_IDX);
  int* vcnt = (int*)(ws + OFF_VC);

  hipMemcpyAsync(xbuf, x, (size_t)ROWS * DIM * sizeof(float),
                 hipMemcpyDeviceToDevice, stream);

  scan_kernel<<<BATCH, 64, 0, stream>>>(vseq, didx, vcnt);

  for (int i = 0; i < DEPTH; ++i) {
    wconv_all_kernel<<<3072, dim3(32, 8), 0, stream>>>(
        wqkv + (size_t)i * DIM * 1536, wout + (size_t)i * DIM * DIM,
        w1 + (size_t)i * DIM * MLP_D, w2 + (size_t)i * MLP_D * DIM,
        wt_qkv, wt_out, wt_w1, wt_w2);

    ln_kernel<<<ROWS / 4, 256, 0, stream>>>(xbuf, ln1g + i * DIM, ln1b + i * DIM, hb);

    gemm_kernel<<<dim3(12, 95), 512, 0, stream>>>(
        hb, wt_qkv, ROWS, 1536, DIM, 3,
        nullptr, nullptr, nullptr, nullptr, qbuf, kbuf, vtbuf, didx);

    attn_kernel<<<dim3(6, BATCH * HEADS), 512, 0, stream>>>(
        qbuf, kbuf, vtbuf, vcnt, obuf);

    gemm_kernel<<<dim3(4, 95), 512, 0, stream>>>(
        obuf, wt_out, ROWS, DIM, DIM, 2,
        xbuf, nullptr, bout + i * DIM, xbuf, nullptr, nullptr, nullptr, nullptr);

    ln_kernel<<<ROWS / 4, 256, 0, stream>>>(xbuf, ln2g + i * DIM, ln2b + i * DIM, hb);

    gemm_kernel<<<dim3(16, 95), 512, 0, stream>>>(
        hb, wt_w1, ROWS, MLP_D, DIM, 1,
        nullptr, ffbuf, b1 + i * MLP_D, nullptr, nullptr, nullptr, nullptr, nullptr);

    gemm_kernel<<<dim3(4, 95), 512, 0, stream>>>(
        ffbuf, wt_w2, ROWS, DIM, MLP_D, 2,
        xbuf, nullptr, b2 + i * DIM, xbuf, nullptr, nullptr, nullptr, nullptr);
  }
}

// Round 18
// 1224.329 us; speedup vs baseline: 1.0103x; 1.0103x over previous
//
#include <hip/hip_runtime.h>

#define DEPTH 6
#define DIM 512
#define HEADS 8
#define DHEAD 64
#define MLP_D 2048
#define SEQ 760
#define SEQP 768
#define BATCH 16
#define ROWS (BATCH * SEQ)      // 12160 = 95 * 128
#define QK_SCALE 0.125f
#define C2LOG (QK_SCALE * 1.44269504089f)   // fold softmax into base-2

typedef float f32x4 __attribute__((ext_vector_type(4)));
typedef __bf16 bf16x8 __attribute__((ext_vector_type(8)));

__device__ inline f32x4 mfma16(bf16x8 a, bf16x8 b, f32x4 c) {
  return __builtin_amdgcn_mfma_f32_16x16x32_bf16(a, b, c, 0, 0, 0);
}

#define GLOAD_LDS(gp, lp) \
  __builtin_amdgcn_global_load_lds( \
      (const __attribute__((address_space(1))) void*)(gp), \
      (__attribute__((address_space(3))) void*)(lp), 16, 0, 0)

// bijective XCD-chunk remap (m204): consecutive remapped ids share an XCD
__device__ inline int swz_flat(int flat, int total) {
  int xcd = flat & 7, idx = flat >> 3;
  int q = total >> 3, r = total & 7;
  return (xcd < r ? xcd * (q + 1) : r * (q + 1) + (xcd - r) * q) + idx;
}

// ---------------- valid-key scan: didx[b][j] = compacted pos or -1; vcnt[b] ----------------
__global__ __launch_bounds__(64) void scan_kernel(
    const int* __restrict__ vseq, int* __restrict__ didx, int* __restrict__ vcnt)
{
  int b = blockIdx.x;
  if (threadIdx.x == 0) {
    int c = 0;
    for (int j = 0; j < SEQ; ++j) {
      bool valid = (j == 0) || (vseq[b * (SEQ - 1) + j - 1] != 0);
      didx[b * SEQ + j] = valid ? c : -1;
      if (valid) ++c;
    }
    vcnt[b] = c;
  }
}

// ---------------- LayerNorm: fp32 in -> bf16 out (one wave per row) ----------------
__global__ __launch_bounds__(256) void ln_kernel(
    const float* __restrict__ x, const float* __restrict__ gw,
    const float* __restrict__ bw, __bf16* __restrict__ out)
{
  int wave = threadIdx.x >> 6, lane = threadIdx.x & 63;
  int row = blockIdx.x * 4 + wave;
  const float4* xr = (const float4*)(x + (size_t)row * DIM);
  float4 a = xr[lane * 2], b = xr[lane * 2 + 1];
  float s  = a.x + a.y + a.z + a.w + b.x + b.y + b.z + b.w;
  float ss = a.x*a.x + a.y*a.y + a.z*a.z + a.w*a.w
           + b.x*b.x + b.y*b.y + b.z*b.z + b.w*b.w;
  #pragma unroll
  for (int m = 1; m < 64; m <<= 1) {
    s  += __shfl_xor(s, m);
    ss += __shfl_xor(ss, m);
  }
  float mu  = s * (1.0f / DIM);
  float var = ss * (1.0f / DIM) - mu * mu;
  float rs  = rsqrtf(var + 1e-5f);
  const float4* gr = (const float4*)gw;
  const float4* br = (const float4*)bw;
  float4 g0 = gr[lane * 2], g1 = gr[lane * 2 + 1];
  float4 b0 = br[lane * 2], b1 = br[lane * 2 + 1];
  bf16x8 o;
  o[0] = (__bf16)((a.x - mu) * rs * g0.x + b0.x);
  o[1] = (__bf16)((a.y - mu) * rs * g0.y + b0.y);
  o[2] = (__bf16)((a.z - mu) * rs * g0.z + b0.z);
  o[3] = (__bf16)((a.w - mu) * rs * g0.w + b0.w);
  o[4] = (__bf16)((b.x - mu) * rs * g1.x + b1.x);
  o[5] = (__bf16)((b.y - mu) * rs * g1.y + b1.y);
  o[6] = (__bf16)((b.z - mu) * rs * g1.z + b1.z);
  o[7] = (__bf16)((b.w - mu) * rs * g1.w + b1.w);
  *(bf16x8*)(out + (size_t)row * DIM + lane * 8) = o;
}

// ---------------- fused weight conversion: all 4 weights of one layer ----------------
__global__ __launch_bounds__(256) void wconv_all_kernel(
    const float* __restrict__ wqkv, const float* __restrict__ wout,
    const float* __restrict__ w1, const float* __restrict__ w2,
    __bf16* __restrict__ tq, __bf16* __restrict__ to,
    __bf16* __restrict__ t1, __bf16* __restrict__ t2)
{
  __shared__ float tile[32][33];
  int id = blockIdx.x;
  const float* W; __bf16* Wt; int K, N, nx, rel;
  if (id < 768)       { W = wqkv; Wt = tq; K = 512;  N = 1536; nx = 48; rel = id; }
  else if (id < 1024) { W = wout; Wt = to; K = 512;  N = 512;  nx = 16; rel = id - 768; }
  else if (id < 2048) { W = w1;   Wt = t1; K = 512;  N = 2048; nx = 64; rel = id - 1024; }
  else                { W = w2;   Wt = t2; K = 2048; N = 512;  nx = 16; rel = id - 2048; }
  int n0 = (rel % nx) * 32, k0 = (rel / nx) * 32;
  int tx = threadIdx.x, ty = threadIdx.y;
  #pragma unroll
  for (int r = ty; r < 32; r += 8)
    tile[r][tx] = W[(size_t)(k0 + r) * N + n0 + tx];
  __syncthreads();
  #pragma unroll
  for (int r = ty; r < 32; r += 8)
    Wt[(size_t)(n0 + r) * K + k0 + tx] = (__bf16)tile[tx][r];
}

// ---------------- GEMM: C[M,N] = A[M,K](bf16) * Bt[N,K]^T (bf16) ----------------
// R10/R13/R15-verified schedule (BEST): 512 threads, 8 waves (4r x 2c, 32x64
// wave tiles), 128x128 tile, BK=64, DOUBLE-buffered, counted vmcnt(4),
// two barriers per K-step, STAGE(t+2) after barrier#2.  T2 both-sides XOR
// swizzle (conflicts 73x down).
// mode 3 scatters K rows / V^T cols to COMPACTED key positions via didx.
#define CS_LD 136   // bf16 bounce stride (elems)
#define CF_LD 132   // f32 bounce stride (elems)
__global__ __launch_bounds__(512, 4) void gemm_kernel(
    const __bf16* __restrict__ A, const __bf16* __restrict__ Bt,
    int M, int N, int K, int mode,
    float* Cf, __bf16* __restrict__ Cb,
    const float* __restrict__ bias, const float* resid,
    __bf16* __restrict__ qo, __bf16* __restrict__ ko, __bf16* __restrict__ vto,
    const int* __restrict__ didx)
{
  __shared__ __align__(16) __bf16 SS[32768];  // 64KB: 2x(A+B) staging; epilogue bounce aliased
  __bf16* A0 = SS;
  __bf16* B0 = SS + 8192;
  __bf16* A1 = SS + 16384;
  __bf16* B1 = SS + 24576;
  int tid = threadIdx.x;
  int lane = tid & 63;
  int wave = tid >> 6;          // 0..7
  int wr = wave >> 1;           // 0..3 : 32-row band
  int wc = wave & 1;            // 0..1 : 64-col band

  int wg = swz_flat(blockIdx.y * gridDim.x + blockIdx.x, gridDim.x * gridDim.y);
  int jblk = wg % gridDim.x;
  int iblk = wg / gridDim.x;

  const __bf16* Ab = A  + (size_t)(iblk * 128) * K;
  const __bf16* Bb = Bt + (size_t)(jblk * 128) * K;
  int srow = tid >> 3;          // 0..63
  // T2: source chunk swizzled so LDS chunk c at row r holds global chunk c^(r&7)
  int scolsw = (((tid & 7) ^ (srow & 7)) * 8);
  f32x4 acc[2][4] = {};

  #define STAGE(k0, Ad, Bd) { \
    _Pragma("unroll") \
    for (int c = 0; c < 2; ++c) { \
      int row = c * 64 + srow; \
      GLOAD_LDS(Ab + (size_t)row * K + (k0) + scolsw, (Ad) + c * 4096 + tid * 8); \
      GLOAD_LDS(Bb + (size_t)row * K + (k0) + scolsw, (Bd) + c * 4096 + tid * 8); \
    } }

  #define COMPUTE(As, Bs) { \
    _Pragma("unroll") \
    for (int kk = 0; kk < 2; ++kk) { \
      int ch = ((kk * 4 + (lane >> 4)) ^ (lane & 7)) * 8; \
      bf16x8 af[2], bfr[4]; \
      _Pragma("unroll") \
      for (int mi = 0; mi < 2; ++mi) \
        af[mi] = *(const bf16x8*)((As) + (wr * 32 + mi * 16 + (lane & 15)) * 64 + ch); \
      _Pragma("unroll") \
      for (int ni = 0; ni < 4; ++ni) \
        bfr[ni] = *(const bf16x8*)((Bs) + (wc * 64 + ni * 16 + (lane & 15)) * 64 + ch); \
      _Pragma("unroll") \
      for (int mi = 0; mi < 2; ++mi) \
        _Pragma("unroll") \
        for (int ni = 0; ni < 4; ++ni) \
          acc[mi][ni] = mfma16(af[mi], bfr[ni], acc[mi][ni]); \
    } }

  int nst = K >> 6;             // >= 8 for all our shapes
  STAGE(0, A0, B0);
  STAGE(64, A1, B1);            // 8 loads in flight
  for (int t = 0; t < nst - 1; ++t) {
    const __bf16* As = (t & 1) ? A1 : A0;
    const __bf16* Bs = (t & 1) ? B1 : B0;
    asm volatile("s_waitcnt vmcnt(4)" ::: "memory");  // tile t landed (own loads)
    __builtin_amdgcn_s_barrier();                      // all waves' tile t landed
    __builtin_amdgcn_sched_barrier(0);
    COMPUTE(As, Bs);
    __builtin_amdgcn_s_barrier();                      // all waves done reading buf t
    if (t + 2 < nst)
      STAGE((t + 2) << 6, (__bf16*)As, (__bf16*)Bs);   // refill the buffer just consumed
  }
  asm volatile("s_waitcnt vmcnt(0)" ::: "memory");
  __builtin_amdgcn_s_barrier();
  __builtin_amdgcn_sched_barrier(0);
  {
    const __bf16* As = ((nst - 1) & 1) ? A1 : A0;
    const __bf16* Bs = ((nst - 1) & 1) ? B1 : B0;
    COMPUTE(As, Bs);
  }
  __syncthreads();   // protect SS reuse by epilogue bounce

  if (mode == 2) {
    float* Csf = (float*)SS;   // 64 x CF_LD half-tile
    #pragma unroll
    for (int h = 0; h < 2; ++h) {
      if (h) __syncthreads();
      if ((wr >> 1) == h) {
        #pragma unroll
        for (int mi = 0; mi < 2; ++mi)
          #pragma unroll
          for (int ni = 0; ni < 4; ++ni) {
            int lr = (wr & 1) * 32 + mi * 16 + (lane >> 4) * 4;
            int lc = wc * 64 + ni * 16 + (lane & 15);
            #pragma unroll
            for (int e = 0; e < 4; ++e)
              Csf[(lr + e) * CF_LD + lc] = acc[mi][ni][e];
          }
      }
      __syncthreads();
      #pragma unroll
      for (int c = 0; c < 4; ++c) {
        int elem = c * 2048 + tid * 4;
        int row = elem >> 7, col = elem & 127;
        float4 v = *(float4*)(Csf + row * CF_LD + col);
        int gi = iblk * 128 + h * 64 + row;
        int gj = jblk * 128 + col;
        float4 bz = *(const float4*)(bias + gj);
        float4 rz = *(const float4*)(resid + (size_t)gi * N + gj);
        v.x += bz.x + rz.x; v.y += bz.y + rz.y;
        v.z += bz.z + rz.z; v.w += bz.w + rz.w;
        *(float4*)(Cf + (size_t)gi * N + gj) = v;
      }
    }
    return;
  }

  if (mode == 3 && jblk >= 8) {
    // V^T: scatter each element to compacted key column didx[n] (2B predicated stores)
    #pragma unroll
    for (int mi = 0; mi < 2; ++mi) {
      int i0 = iblk * 128 + wr * 32 + mi * 16 + (lane >> 4) * 4;
      int b = i0 / SEQ;                // i0%4==0 and SEQ%4==0 -> same b for 4 e's
      int n0 = i0 - b * SEQ;
      int dn[4];
      #pragma unroll
      for (int e = 0; e < 4; ++e) dn[e] = didx[b * SEQ + n0 + e];  // hoisted
      #pragma unroll
      for (int ni = 0; ni < 4; ++ni) {
        int j = (jblk - 8) * 128 + wc * 64 + ni * 16 + (lane & 15);  // 0..511
        int hh = j >> 6, d = j & 63;
        __bf16* vbase = vto + ((size_t)(b * HEADS + hh) * DHEAD + d) * SEQP;
        #pragma unroll
        for (int e = 0; e < 4; ++e)
          if (dn[e] >= 0) vbase[dn[e]] = (__bf16)acc[mi][ni][e];
      }
    }
    return;
  }

  // bf16 bounce: modes 0, 1, 3(q/k)
  __bf16* Cs = SS;
  #pragma unroll
  for (int mi = 0; mi < 2; ++mi)
    #pragma unroll
    for (int ni = 0; ni < 4; ++ni) {
      int lr = wr * 32 + mi * 16 + (lane >> 4) * 4;
      int lc = wc * 64 + ni * 16 + (lane & 15);
      #pragma unroll
      for (int e = 0; e < 4; ++e) {
        float v = acc[mi][ni][e];
        if (mode == 1) {
          v += bias[jblk * 128 + lc];
          v = 0.5f * v * (1.0f + erff(v * 0.70710678118654752f));
        }
        Cs[(lr + e) * CS_LD + lc] = (__bf16)v;
      }
    }
  __syncthreads();
  #pragma unroll
  for (int c = 0; c < 4; ++c) {
    int elem = c * 4096 + tid * 8;
    int row = elem >> 7, col = elem & 127;
    bf16x8 v = *(bf16x8*)(Cs + row * CS_LD + col);
    int gi = iblk * 128 + row;
    if (mode <= 1) {
      *(bf16x8*)(Cb + (size_t)gi * N + jblk * 128 + col) = v;
    } else {
      int b = gi / SEQ;
      int n = gi - b * SEQ;
      int j = jblk * 128 + col;
      int hh = (j >> 6) & 7, d = j & 63;
      size_t bh = (size_t)(b * HEADS + hh);
      if (jblk < 4) {
        *(bf16x8*)(qo + (bh * SEQ + n) * DHEAD + d) = v;
      } else {
        int dn = didx[b * SEQ + n];
        if (dn >= 0) *(bf16x8*)(ko + (bh * SEQP + dn) * DHEAD + d) = v;
      }
    }
  }
}

// ---------------- Flash attention over COMPACTED keys ----------------
// R13-verified: 8 waves x 16 q-rows; global_load_lds staging (linear [64][64]
// LDS, T2 both-sides XOR swizzle), double-buffered counted vmcnt(2).
#define KVB 64
#define PS_LD 68
__global__ __launch_bounds__(512, 3) void attn_kernel(
    const __bf16* __restrict__ qb, const __bf16* __restrict__ kb,
    const __bf16* __restrict__ vtb, const int* __restrict__ vcnt,
    __bf16* __restrict__ ob)
{
  __shared__ __align__(16) __bf16 KV[4 * KVB * DHEAD];   // K0,V0,K1,V1 : 32KB linear
  __shared__ __align__(16) __bf16 Ps[8][16 * PS_LD];     // per-wave P bounce
  __bf16* K0 = KV;
  __bf16* V0 = KV + 4096;
  __bf16* K1 = KV + 8192;
  __bf16* V1 = KV + 12288;
  int tid = threadIdx.x, lane = tid & 63, wave = tid >> 6;

  int wg = swz_flat(blockIdx.y * gridDim.x + blockIdx.x, gridDim.x * gridDim.y);
  int qblk = wg % gridDim.x;       // 0..5
  int bh   = wg / gridDim.x;       // 0..127
  int b = bh >> 3, hh = bh & 7;
  int q0 = qblk * 128 + wave * 16;

  int vc = vcnt[b];
  int nt = (vc + KVB - 1) >> 6;    // >=1 (key 0 always valid)

  const __bf16* qbase = qb  + (size_t)bh * SEQ * DHEAD;
  const __bf16* kbase = kb  + (size_t)bh * SEQP * DHEAD;
  const __bf16* vbase = vtb + (size_t)bh * DHEAD * SEQP;

  int qrow = q0 + (lane & 15);
  if (qrow > SEQ - 1) qrow = SEQ - 1;
  bf16x8 qf[2];
  #pragma unroll
  for (int ks = 0; ks < 2; ++ks)
    qf[ks] = *(const bf16x8*)(qbase + (size_t)qrow * DHEAD + ks * 32 + (lane >> 4) * 8);

  f32x4 oacc[4] = {};
  float mi[4] = {-INFINITY, -INFINITY, -INFINITY, -INFINITY};
  float li[4] = {0.f, 0.f, 0.f, 0.f};   // per-lane partial, reduced once at end

  // drain q loads so manual vmcnt counting below sees only gload_lds ops
  asm volatile("s_waitcnt vmcnt(0)" ::: "memory");

  // staging geometry: thread -> (row = tid>>3, chunk = tid&7); LDS dest linear
  // tid*16B; source chunk pre-swizzled by (row&7) so LDS[r][c] = global[r][c^(r&7)].
  // buffers are SEQP=768 wide -> all tile loads in-bounds; tail keys masked.
  int srow = tid >> 3;
  int schx = ((tid & 7) ^ (srow & 7)) * 8;

  #define ASTAGE(kt, Kd, Vd) { \
    GLOAD_LDS(kbase + (size_t)((kt) * KVB + srow) * DHEAD + schx, (Kd) + tid * 8); \
    GLOAD_LDS(vbase + (size_t)srow * SEQP + (kt) * KVB + schx, (Vd) + tid * 8); }

  ASTAGE(0, K0, V0);
  if (nt > 1) ASTAGE(1, K1, V1);

  for (int kt = 0; kt < nt; ++kt) {
    const __bf16* Ks = (kt & 1) ? K1 : K0;
    const __bf16* Vs = (kt & 1) ? V1 : V0;
    if (kt + 1 < nt) { asm volatile("s_waitcnt vmcnt(2)" ::: "memory"); }
    else             { asm volatile("s_waitcnt vmcnt(0)" ::: "memory"); }
    __builtin_amdgcn_s_barrier();           // all waves' tile kt landed
    __builtin_amdgcn_sched_barrier(0);

    float addf[4];
    #pragma unroll
    for (int sj = 0; sj < 4; ++sj)
      addf[sj] = (kt * KVB + sj * 16 + (lane & 15) < vc) ? 0.0f : -1e9f;

    f32x4 s[4] = {};
    __builtin_amdgcn_s_setprio(1);
    #pragma unroll
    for (int ks = 0; ks < 2; ++ks) {
      int ch = ((ks * 4 + (lane >> 4)) ^ (lane & 7)) * 8;
      #pragma unroll
      for (int sj = 0; sj < 4; ++sj) {
        bf16x8 kf = *(const bf16x8*)(Ks + (sj * 16 + (lane & 15)) * DHEAD + ch);
        s[sj] = mfma16(qf[ks], kf, s[sj]);
      }
    }
    __builtin_amdgcn_s_setprio(0);
    #pragma unroll
    for (int sj = 0; sj < 4; ++sj)
      #pragma unroll
      for (int e = 0; e < 4; ++e)
        s[sj][e] = fmaf(s[sj][e], C2LOG, addf[sj]);

    float vmax[4];
    #pragma unroll
    for (int e = 0; e < 4; ++e) {
      float v = fmaxf(fmaxf(s[0][e], s[1][e]), fmaxf(s[2][e], s[3][e]));
      v = fmaxf(v, __shfl_xor(v, 1));
      v = fmaxf(v, __shfl_xor(v, 2));
      v = fmaxf(v, __shfl_xor(v, 4));
      v = fmaxf(v, __shfl_xor(v, 8));
      vmax[e] = v;
    }
    // defer-max: only rescale when some row grew past mi + 11 (2^11 P-headroom)
    bool need = false;
    #pragma unroll
    for (int e = 0; e < 4; ++e) need |= (vmax[e] > mi[e] + 11.0f);
    if (__any(need)) {
      #pragma unroll
      for (int e = 0; e < 4; ++e) {
        float mnew = fmaxf(mi[e], vmax[e]);
        float alpha = exp2f(mi[e] - mnew);
        mi[e] = mnew;
        li[e] *= alpha;
        #pragma unroll
        for (int dj = 0; dj < 4; ++dj)
          oacc[dj][e] *= alpha;
      }
    }
    #pragma unroll
    for (int e = 0; e < 4; ++e) {
      float sum = 0.f;
      #pragma unroll
      for (int sj = 0; sj < 4; ++sj) {
        float p = exp2f(s[sj][e] - mi[e]);
        s[sj][e] = p;
        sum += p;
      }
      li[e] += sum;
    }

    // P (D-layout) -> per-wave LDS -> A-layout fragments
    #pragma unroll
    for (int sj = 0; sj < 4; ++sj)
      #pragma unroll
      for (int e = 0; e < 4; ++e)
        Ps[wave][((lane >> 4) * 4 + e) * PS_LD + sj * 16 + (lane & 15)] = (__bf16)s[sj][e];
    bf16x8 pf[2];
    #pragma unroll
    for (int c = 0; c < 2; ++c)
      pf[c] = *(const bf16x8*)(&Ps[wave][(lane & 15) * PS_LD + c * 32 + (lane >> 4) * 8]);
    __builtin_amdgcn_s_setprio(1);
    #pragma unroll
    for (int dj = 0; dj < 4; ++dj) {
      #pragma unroll
      for (int c = 0; c < 2; ++c) {
        int ch = ((c * 4 + (lane >> 4)) ^ (lane & 7)) * 8;
        bf16x8 vf = *(const bf16x8*)(Vs + (dj * 16 + (lane & 15)) * DHEAD + ch);
        oacc[dj] = mfma16(pf[c], vf, oacc[dj]);
      }
    }
    __builtin_amdgcn_s_setprio(0);

    __builtin_amdgcn_s_barrier();           // all waves done reading buffers kt
    if (kt + 2 < nt) {
      __bf16* Kn = (kt & 1) ? K1 : K0;      // buffer (kt+2)&1 = just-consumed one
      __bf16* Vn = (kt & 1) ? V1 : V0;
      ASTAGE(kt + 2, Kn, Vn);
    }
  }

  // final cross-lane l reduction (once, instead of per tile)
  #pragma unroll
  for (int e = 0; e < 4; ++e) {
    float l = li[e];
    l += __shfl_xor(l, 1);
    l += __shfl_xor(l, 2);
    l += __shfl_xor(l, 4);
    l += __shfl_xor(l, 8);
    li[e] = l;
  }

  #pragma unroll
  for (int e = 0; e < 4; ++e) {
    int n = q0 + (lane >> 4) * 4 + e;
    if (n < SEQ) {
      float inv = 1.0f / li[e];
      #pragma unroll
      for (int dj = 0; dj < 4; ++dj)
        ob[((size_t)b * SEQ + n) * DIM + hh * DHEAD + dj * 16 + (lane & 15)] =
            (__bf16)(oacc[dj][e] * inv);
    }
  }
}

// ---------------- workspace layout (bytes) ----------------
static const size_t OFF_WTQKV = 0;                               // 1536*512*2
static const size_t OFF_WTOUT = 1572864;                         // 512*512*2
static const size_t OFF_WTW1  = OFF_WTOUT + 524288;              // 2048*512*2
static const size_t OFF_WTW2  = OFF_WTW1 + 2097152;              // 512*2048*2
static const size_t OFF_H     = OFF_WTW2 + 2097152;              // 12160*512*2
static const size_t OFF_Q     = OFF_H  + 12451840;               // 128*760*64*2
static const size_t OFF_K     = OFF_Q  + 12451840;               // 128*768*64*2
static const size_t OFF_VT    = OFF_K  + 12582912;               // 128*64*768*2
static const size_t OFF_O     = OFF_VT + 12582912;               // 12160*512*2
static const size_t OFF_IDX   = OFF_O  + 12451840;               // 16*760*4
static const size_t OFF_VC    = OFF_IDX + 49152;                 // 16*4
static const size_t OFF_FF    = OFF_Q;  // ff aliases q/k/vt/o (dead by then)

extern "C" void kernel_launch(void* const* d_in, const int* in_sizes, int n_in,
                              void* d_out, int out_size, void* d_ws, size_t ws_size,
                              hipStream_t stream) {
  const float* x    = (const float*)d_in[0];
  const int*   vseq = (const int*)d_in[1];
  const float* ln1g = (const float*)d_in[3];
  const float* ln1b = (const float*)d_in[4];
  const float* wqkv = (const float*)d_in[5];
  const float* wout = (const float*)d_in[6];
  const float* bout = (const float*)d_in[7];
  const float* ln2g = (const float*)d_in[8];
  const float* ln2b = (const float*)d_in[9];
  const float* w1   = (const float*)d_in[10];
  const float* b1   = (const float*)d_in[11];
  const float* w2   = (const float*)d_in[12];
  const float* b2   = (const float*)d_in[13];

  float* xbuf = (float*)d_out;
  char* ws = (char*)d_ws;
  __bf16* wt_qkv = (__bf16*)(ws + OFF_WTQKV);
  __bf16* wt_out = (__bf16*)(ws + OFF_WTOUT);
  __bf16* wt_w1  = (__bf16*)(ws + OFF_WTW1);
  __bf16* wt_w2  = (__bf16*)(ws + OFF_WTW2);
  __bf16* hb     = (__bf16*)(ws + OFF_H);
  __bf16* qbuf   = (__bf16*)(ws + OFF_Q);
  __bf16* kbuf   = (__bf16*)(ws + OFF_K);
  __bf16* vtbuf  = (__bf16*)(ws + OFF_VT);
  __bf16* obuf   = (__bf16*)(ws + OFF_O);
  __bf16* ffbuf  = (__bf16*)(ws + OFF_FF);
  int* didx = (int*)(ws + OFF_IDX);
  int* vcnt = (int*)(ws + OFF_VC);

  scan_kernel<<<BATCH, 64, 0, stream>>>(vseq, didx, vcnt);

  for (int i = 0; i < DEPTH; ++i) {
    // layer 0 reads the input residual stream directly; xbuf (d_out) is fully
    // written by the first mode-2 dispatch before anything reads it
    const float* xin = (i == 0) ? x : xbuf;

    wconv_all_kernel<<<3072, dim3(32, 8), 0, stream>>>(
        wqkv + (size_t)i * DIM * 1536, wout + (size_t)i * DIM * DIM,
        w1 + (size_t)i * DIM * MLP_D, w2 + (size_t)i * MLP_D * DIM,
        wt_qkv, wt_out, wt_w1, wt_w2);

    ln_kernel<<<ROWS / 4, 256, 0, stream>>>(xin, ln1g + i * DIM, ln1b + i * DIM, hb);

    gemm_kernel<<<dim3(12, 95), 512, 0, stream>>>(
        hb, wt_qkv, ROWS, 1536, DIM, 3,
        nullptr, nullptr, nullptr, nullptr, qbuf, kbuf, vtbuf, didx);

    attn_kernel<<<dim3(6, BATCH * HEADS), 512, 0, stream>>>(
        qbuf, kbuf, vtbuf, vcnt, obuf);

    gemm_kernel<<<dim3(4, 95), 512, 0, stream>>>(
        obuf, wt_out, ROWS, DIM, DIM, 2,
        xbuf, nullptr, bout + i * DIM, xin, nullptr, nullptr, nullptr, nullptr);

    ln_kernel<<<ROWS / 4, 256, 0, stream>>>(xbuf, ln2g + i * DIM, ln2b + i * DIM, hb);

    gemm_kernel<<<dim3(16, 95), 512, 0, stream>>>(
        hb, wt_w1, ROWS, MLP_D, DIM, 1,
        nullptr, ffbuf, b1 + i * MLP_D, nullptr, nullptr, nullptr, nullptr, nullptr);

    gemm_kernel<<<dim3(4, 95), 512, 0, stream>>>(
        ffbuf, wt_w2, ROWS, DIM, MLP_D, 2,
        xbuf, nullptr, b2 + i * DIM, xbuf, nullptr, nullptr, nullptr, nullptr);
  }
}

// Round 19
// 1207.714 us; speedup vs baseline: 1.0242x; 1.0138x over previous
//
#include <hip/hip_runtime.h>

#define DEPTH 6
#define DIM 512
#define HEADS 8
#define DHEAD 64
#define MLP_D 2048
#define SEQ 760
#define SEQP 768
#define BATCH 16
#define ROWS (BATCH * SEQ)      // 12160 = 95 * 128
#define QK_SCALE 0.125f
#define C2LOG (QK_SCALE * 1.44269504089f)   // fold softmax into base-2

typedef float f32x4 __attribute__((ext_vector_type(4)));
typedef __bf16 bf16x8 __attribute__((ext_vector_type(8)));

__device__ inline f32x4 mfma16(bf16x8 a, bf16x8 b, f32x4 c) {
  return __builtin_amdgcn_mfma_f32_16x16x32_bf16(a, b, c, 0, 0, 0);
}

#define GLOAD_LDS(gp, lp) \
  __builtin_amdgcn_global_load_lds( \
      (const __attribute__((address_space(1))) void*)(gp), \
      (__attribute__((address_space(3))) void*)(lp), 16, 0, 0)

// bijective XCD-chunk remap (m204): consecutive remapped ids share an XCD
__device__ inline int swz_flat(int flat, int total) {
  int xcd = flat & 7, idx = flat >> 3;
  int q = total >> 3, r = total & 7;
  return (xcd < r ? xcd * (q + 1) : r * (q + 1) + (xcd - r) * q) + idx;
}

// ---------------- valid-key scan: didx[b][j] = compacted pos or -1; vcnt[b] ----------------
__global__ __launch_bounds__(64) void scan_kernel(
    const int* __restrict__ vseq, int* __restrict__ didx, int* __restrict__ vcnt)
{
  int b = blockIdx.x;
  if (threadIdx.x == 0) {
    int c = 0;
    for (int j = 0; j < SEQ; ++j) {
      bool valid = (j == 0) || (vseq[b * (SEQ - 1) + j - 1] != 0);
      didx[b * SEQ + j] = valid ? c : -1;
      if (valid) ++c;
    }
    vcnt[b] = c;
  }
}

// ---------------- LayerNorm: fp32 in -> bf16 out (one wave per row) ----------------
__global__ __launch_bounds__(256) void ln_kernel(
    const float* __restrict__ x, const float* __restrict__ gw,
    const float* __restrict__ bw, __bf16* __restrict__ out)
{
  int wave = threadIdx.x >> 6, lane = threadIdx.x & 63;
  int row = blockIdx.x * 4 + wave;
  const float4* xr = (const float4*)(x + (size_t)row * DIM);
  float4 a = xr[lane * 2], b = xr[lane * 2 + 1];
  float s  = a.x + a.y + a.z + a.w + b.x + b.y + b.z + b.w;
  float ss = a.x*a.x + a.y*a.y + a.z*a.z + a.w*a.w
           + b.x*b.x + b.y*b.y + b.z*b.z + b.w*b.w;
  #pragma unroll
  for (int m = 1; m < 64; m <<= 1) {
    s  += __shfl_xor(s, m);
    ss += __shfl_xor(ss, m);
  }
  float mu  = s * (1.0f / DIM);
  float var = ss * (1.0f / DIM) - mu * mu;
  float rs  = rsqrtf(var + 1e-5f);
  const float4* gr = (const float4*)gw;
  const float4* br = (const float4*)bw;
  float4 g0 = gr[lane * 2], g1 = gr[lane * 2 + 1];
  float4 b0 = br[lane * 2], b1 = br[lane * 2 + 1];
  bf16x8 o;
  o[0] = (__bf16)((a.x - mu) * rs * g0.x + b0.x);
  o[1] = (__bf16)((a.y - mu) * rs * g0.y + b0.y);
  o[2] = (__bf16)((a.z - mu) * rs * g0.z + b0.z);
  o[3] = (__bf16)((a.w - mu) * rs * g0.w + b0.w);
  o[4] = (__bf16)((b.x - mu) * rs * g1.x + b1.x);
  o[5] = (__bf16)((b.y - mu) * rs * g1.y + b1.y);
  o[6] = (__bf16)((b.z - mu) * rs * g1.z + b1.z);
  o[7] = (__bf16)((b.w - mu) * rs * g1.w + b1.w);
  *(bf16x8*)(out + (size_t)row * DIM + lane * 8) = o;
}

// ---------------- weight conversion core: fp32 [K,N] block -> bf16 [N,K]^T ----------------
__device__ inline void wconv_block(const float* W, __bf16* Wt, int K, int N,
                                   int nx, int rel, float tile[32][33],
                                   int tx, int ty)
{
  int n0 = (rel % nx) * 32, k0 = (rel / nx) * 32;
  #pragma unroll
  for (int r = ty; r < 32; r += 8)
    tile[r][tx] = W[(size_t)(k0 + r) * N + n0 + tx];
  __syncthreads();
  #pragma unroll
  for (int r = ty; r < 32; r += 8)
    Wt[(size_t)(n0 + r) * K + k0 + tx] = (__bf16)tile[tx][r];
}

// per-layer slab layout (bytes): tq 0 | to 1572864 | t1 2097152 | t2 4194304
#define SLAB 6291456

// ---------------- per-layer wconv (fallback path, R18-identical) ----------------
__global__ __launch_bounds__(256) void wconv_all_kernel(
    const float* __restrict__ wqkv, const float* __restrict__ wout,
    const float* __restrict__ w1, const float* __restrict__ w2,
    char* __restrict__ slab)
{
  __shared__ float tile[32][33];
  int id = blockIdx.x;
  int tx = threadIdx.x, ty = threadIdx.y;
  if (id < 768)
    wconv_block(wqkv, (__bf16*)(slab + 0), 512, 1536, 48, id, tile, tx, ty);
  else if (id < 1024)
    wconv_block(wout, (__bf16*)(slab + 1572864), 512, 512, 16, id - 768, tile, tx, ty);
  else if (id < 2048)
    wconv_block(w1, (__bf16*)(slab + 2097152), 512, 2048, 64, id - 1024, tile, tx, ty);
  else
    wconv_block(w2, (__bf16*)(slab + 4194304), 2048, 512, 16, id - 2048, tile, tx, ty);
}

// ---------------- all-6-layers wconv (hoisted path, one launch) ----------------
__global__ __launch_bounds__(256) void wconv_all6_kernel(
    const float* __restrict__ wqkv, const float* __restrict__ wout,
    const float* __restrict__ w1, const float* __restrict__ w2,
    char* __restrict__ ws, size_t off_extra)
{
  __shared__ float tile[32][33];
  int L = blockIdx.x / 3072;
  int id = blockIdx.x % 3072;
  int tx = threadIdx.x, ty = threadIdx.y;
  char* slab = ws + (L == 0 ? (size_t)0 : off_extra + (size_t)(L - 1) * SLAB);
  const float* wq = wqkv + (size_t)L * DIM * 1536;
  const float* wo = wout + (size_t)L * DIM * DIM;
  const float* wa = w1   + (size_t)L * DIM * MLP_D;
  const float* wb = w2   + (size_t)L * MLP_D * DIM;
  if (id < 768)
    wconv_block(wq, (__bf16*)(slab + 0), 512, 1536, 48, id, tile, tx, ty);
  else if (id < 1024)
    wconv_block(wo, (__bf16*)(slab + 1572864), 512, 512, 16, id - 768, tile, tx, ty);
  else if (id < 2048)
    wconv_block(wa, (__bf16*)(slab + 2097152), 512, 2048, 64, id - 1024, tile, tx, ty);
  else
    wconv_block(wb, (__bf16*)(slab + 4194304), 2048, 512, 16, id - 2048, tile, tx, ty);
}

// ---------------- GEMM: C[M,N] = A[M,K](bf16) * Bt[N,K]^T (bf16) ----------------
// R10/R13/R15-verified schedule (BEST): 512 threads, 8 waves (4r x 2c, 32x64
// wave tiles), 128x128 tile, BK=64, DOUBLE-buffered, counted vmcnt(4),
// two barriers per K-step, STAGE(t+2) after barrier#2.  T2 both-sides XOR
// swizzle (conflicts 73x down).
// mode 3 scatters K rows / V^T cols to COMPACTED key positions via didx.
#define CS_LD 136   // bf16 bounce stride (elems)
#define CF_LD 132   // f32 bounce stride (elems)
__global__ __launch_bounds__(512, 4) void gemm_kernel(
    const __bf16* __restrict__ A, const __bf16* __restrict__ Bt,
    int M, int N, int K, int mode,
    float* Cf, __bf16* __restrict__ Cb,
    const float* __restrict__ bias, const float* resid,
    __bf16* __restrict__ qo, __bf16* __restrict__ ko, __bf16* __restrict__ vto,
    const int* __restrict__ didx)
{
  __shared__ __align__(16) __bf16 SS[32768];  // 64KB: 2x(A+B) staging; epilogue bounce aliased
  __bf16* A0 = SS;
  __bf16* B0 = SS + 8192;
  __bf16* A1 = SS + 16384;
  __bf16* B1 = SS + 24576;
  int tid = threadIdx.x;
  int lane = tid & 63;
  int wave = tid >> 6;          // 0..7
  int wr = wave >> 1;           // 0..3 : 32-row band
  int wc = wave & 1;            // 0..1 : 64-col band

  int wg = swz_flat(blockIdx.y * gridDim.x + blockIdx.x, gridDim.x * gridDim.y);
  int jblk = wg % gridDim.x;
  int iblk = wg / gridDim.x;

  const __bf16* Ab = A  + (size_t)(iblk * 128) * K;
  const __bf16* Bb = Bt + (size_t)(jblk * 128) * K;
  int srow = tid >> 3;          // 0..63
  // T2: source chunk swizzled so LDS chunk c at row r holds global chunk c^(r&7)
  int scolsw = (((tid & 7) ^ (srow & 7)) * 8);
  f32x4 acc[2][4] = {};

  #define STAGE(k0, Ad, Bd) { \
    _Pragma("unroll") \
    for (int c = 0; c < 2; ++c) { \
      int row = c * 64 + srow; \
      GLOAD_LDS(Ab + (size_t)row * K + (k0) + scolsw, (Ad) + c * 4096 + tid * 8); \
      GLOAD_LDS(Bb + (size_t)row * K + (k0) + scolsw, (Bd) + c * 4096 + tid * 8); \
    } }

  #define COMPUTE(As, Bs) { \
    _Pragma("unroll") \
    for (int kk = 0; kk < 2; ++kk) { \
      int ch = ((kk * 4 + (lane >> 4)) ^ (lane & 7)) * 8; \
      bf16x8 af[2], bfr[4]; \
      _Pragma("unroll") \
      for (int mi = 0; mi < 2; ++mi) \
        af[mi] = *(const bf16x8*)((As) + (wr * 32 + mi * 16 + (lane & 15)) * 64 + ch); \
      _Pragma("unroll") \
      for (int ni = 0; ni < 4; ++ni) \
        bfr[ni] = *(const bf16x8*)((Bs) + (wc * 64 + ni * 16 + (lane & 15)) * 64 + ch); \
      _Pragma("unroll") \
      for (int mi = 0; mi < 2; ++mi) \
        _Pragma("unroll") \
        for (int ni = 0; ni < 4; ++ni) \
          acc[mi][ni] = mfma16(af[mi], bfr[ni], acc[mi][ni]); \
    } }

  int nst = K >> 6;             // >= 8 for all our shapes
  STAGE(0, A0, B0);
  STAGE(64, A1, B1);            // 8 loads in flight
  for (int t = 0; t < nst - 1; ++t) {
    const __bf16* As = (t & 1) ? A1 : A0;
    const __bf16* Bs = (t & 1) ? B1 : B0;
    asm volatile("s_waitcnt vmcnt(4)" ::: "memory");  // tile t landed (own loads)
    __builtin_amdgcn_s_barrier();                      // all waves' tile t landed
    __builtin_amdgcn_sched_barrier(0);
    COMPUTE(As, Bs);
    __builtin_amdgcn_s_barrier();                      // all waves done reading buf t
    if (t + 2 < nst)
      STAGE((t + 2) << 6, (__bf16*)As, (__bf16*)Bs);   // refill the buffer just consumed
  }
  asm volatile("s_waitcnt vmcnt(0)" ::: "memory");
  __builtin_amdgcn_s_barrier();
  __builtin_amdgcn_sched_barrier(0);
  {
    const __bf16* As = ((nst - 1) & 1) ? A1 : A0;
    const __bf16* Bs = ((nst - 1) & 1) ? B1 : B0;
    COMPUTE(As, Bs);
  }
  __syncthreads();   // protect SS reuse by epilogue bounce

  if (mode == 2) {
    float* Csf = (float*)SS;   // 64 x CF_LD half-tile
    #pragma unroll
    for (int h = 0; h < 2; ++h) {
      if (h) __syncthreads();
      if ((wr >> 1) == h) {
        #pragma unroll
        for (int mi = 0; mi < 2; ++mi)
          #pragma unroll
          for (int ni = 0; ni < 4; ++ni) {
            int lr = (wr & 1) * 32 + mi * 16 + (lane >> 4) * 4;
            int lc = wc * 64 + ni * 16 + (lane & 15);
            #pragma unroll
            for (int e = 0; e < 4; ++e)
              Csf[(lr + e) * CF_LD + lc] = acc[mi][ni][e];
          }
      }
      __syncthreads();
      #pragma unroll
      for (int c = 0; c < 4; ++c) {
        int elem = c * 2048 + tid * 4;
        int row = elem >> 7, col = elem & 127;
        float4 v = *(float4*)(Csf + row * CF_LD + col);
        int gi = iblk * 128 + h * 64 + row;
        int gj = jblk * 128 + col;
        float4 bz = *(const float4*)(bias + gj);
        float4 rz = *(const float4*)(resid + (size_t)gi * N + gj);
        v.x += bz.x + rz.x; v.y += bz.y + rz.y;
        v.z += bz.z + rz.z; v.w += bz.w + rz.w;
        *(float4*)(Cf + (size_t)gi * N + gj) = v;
      }
    }
    return;
  }

  if (mode == 3 && jblk >= 8) {
    // V^T: scatter each element to compacted key column didx[n] (2B predicated stores)
    #pragma unroll
    for (int mi = 0; mi < 2; ++mi) {
      int i0 = iblk * 128 + wr * 32 + mi * 16 + (lane >> 4) * 4;
      int b = i0 / SEQ;                // i0%4==0 and SEQ%4==0 -> same b for 4 e's
      int n0 = i0 - b * SEQ;
      int dn[4];
      #pragma unroll
      for (int e = 0; e < 4; ++e) dn[e] = didx[b * SEQ + n0 + e];  // hoisted
      #pragma unroll
      for (int ni = 0; ni < 4; ++ni) {
        int j = (jblk - 8) * 128 + wc * 64 + ni * 16 + (lane & 15);  // 0..511
        int hh = j >> 6, d = j & 63;
        __bf16* vbase = vto + ((size_t)(b * HEADS + hh) * DHEAD + d) * SEQP;
        #pragma unroll
        for (int e = 0; e < 4; ++e)
          if (dn[e] >= 0) vbase[dn[e]] = (__bf16)acc[mi][ni][e];
      }
    }
    return;
  }

  // bf16 bounce: modes 0, 1, 3(q/k)
  __bf16* Cs = SS;
  #pragma unroll
  for (int mi = 0; mi < 2; ++mi)
    #pragma unroll
    for (int ni = 0; ni < 4; ++ni) {
      int lr = wr * 32 + mi * 16 + (lane >> 4) * 4;
      int lc = wc * 64 + ni * 16 + (lane & 15);
      #pragma unroll
      for (int e = 0; e < 4; ++e) {
        float v = acc[mi][ni][e];
        if (mode == 1) {
          v += bias[jblk * 128 + lc];
          v = 0.5f * v * (1.0f + erff(v * 0.70710678118654752f));
        }
        Cs[(lr + e) * CS_LD + lc] = (__bf16)v;
      }
    }
  __syncthreads();
  #pragma unroll
  for (int c = 0; c < 4; ++c) {
    int elem = c * 4096 + tid * 8;
    int row = elem >> 7, col = elem & 127;
    bf16x8 v = *(bf16x8*)(Cs + row * CS_LD + col);
    int gi = iblk * 128 + row;
    if (mode <= 1) {
      *(bf16x8*)(Cb + (size_t)gi * N + jblk * 128 + col) = v;
    } else {
      int b = gi / SEQ;
      int n = gi - b * SEQ;
      int j = jblk * 128 + col;
      int hh = (j >> 6) & 7, d = j & 63;
      size_t bh = (size_t)(b * HEADS + hh);
      if (jblk < 4) {
        *(bf16x8*)(qo + (bh * SEQ + n) * DHEAD + d) = v;
      } else {
        int dn = didx[b * SEQ + n];
        if (dn >= 0) *(bf16x8*)(ko + (bh * SEQP + dn) * DHEAD + d) = v;
      }
    }
  }
}

// ---------------- Flash attention over COMPACTED keys ----------------
// R13-verified: 8 waves x 16 q-rows; global_load_lds staging (linear [64][64]
// LDS, T2 both-sides XOR swizzle), double-buffered counted vmcnt(2).
#define KVB 64
#define PS_LD 68
__global__ __launch_bounds__(512, 3) void attn_kernel(
    const __bf16* __restrict__ qb, const __bf16* __restrict__ kb,
    const __bf16* __restrict__ vtb, const int* __restrict__ vcnt,
    __bf16* __restrict__ ob)
{
  __shared__ __align__(16) __bf16 KV[4 * KVB * DHEAD];   // K0,V0,K1,V1 : 32KB linear
  __shared__ __align__(16) __bf16 Ps[8][16 * PS_LD];     // per-wave P bounce
  __bf16* K0 = KV;
  __bf16* V0 = KV + 4096;
  __bf16* K1 = KV + 8192;
  __bf16* V1 = KV + 12288;
  int tid = threadIdx.x, lane = tid & 63, wave = tid >> 6;

  int wg = swz_flat(blockIdx.y * gridDim.x + blockIdx.x, gridDim.x * gridDim.y);
  int qblk = wg % gridDim.x;       // 0..5
  int bh   = wg / gridDim.x;       // 0..127
  int b = bh >> 3, hh = bh & 7;
  int q0 = qblk * 128 + wave * 16;

  int vc = vcnt[b];
  int nt = (vc + KVB - 1) >> 6;    // >=1 (key 0 always valid)

  const __bf16* qbase = qb  + (size_t)bh * SEQ * DHEAD;
  const __bf16* kbase = kb  + (size_t)bh * SEQP * DHEAD;
  const __bf16* vbase = vtb + (size_t)bh * DHEAD * SEQP;

  int qrow = q0 + (lane & 15);
  if (qrow > SEQ - 1) qrow = SEQ - 1;
  bf16x8 qf[2];
  #pragma unroll
  for (int ks = 0; ks < 2; ++ks)
    qf[ks] = *(const bf16x8*)(qbase + (size_t)qrow * DHEAD + ks * 32 + (lane >> 4) * 8);

  f32x4 oacc[4] = {};
  float mi[4] = {-INFINITY, -INFINITY, -INFINITY, -INFINITY};
  float li[4] = {0.f, 0.f, 0.f, 0.f};   // per-lane partial, reduced once at end

  // drain q loads so manual vmcnt counting below sees only gload_lds ops
  asm volatile("s_waitcnt vmcnt(0)" ::: "memory");

  // staging geometry: thread -> (row = tid>>3, chunk = tid&7); LDS dest linear
  // tid*16B; source chunk pre-swizzled by (row&7) so LDS[r][c] = global[r][c^(r&7)].
  // buffers are SEQP=768 wide -> all tile loads in-bounds; tail keys masked.
  int srow = tid >> 3;
  int schx = ((tid & 7) ^ (srow & 7)) * 8;

  #define ASTAGE(kt, Kd, Vd) { \
    GLOAD_LDS(kbase + (size_t)((kt) * KVB + srow) * DHEAD + schx, (Kd) + tid * 8); \
    GLOAD_LDS(vbase + (size_t)srow * SEQP + (kt) * KVB + schx, (Vd) + tid * 8); }

  ASTAGE(0, K0, V0);
  if (nt > 1) ASTAGE(1, K1, V1);

  for (int kt = 0; kt < nt; ++kt) {
    const __bf16* Ks = (kt & 1) ? K1 : K0;
    const __bf16* Vs = (kt & 1) ? V1 : V0;
    if (kt + 1 < nt) { asm volatile("s_waitcnt vmcnt(2)" ::: "memory"); }
    else             { asm volatile("s_waitcnt vmcnt(0)" ::: "memory"); }
    __builtin_amdgcn_s_barrier();           // all waves' tile kt landed
    __builtin_amdgcn_sched_barrier(0);

    float addf[4];
    #pragma unroll
    for (int sj = 0; sj < 4; ++sj)
      addf[sj] = (kt * KVB + sj * 16 + (lane & 15) < vc) ? 0.0f : -1e9f;

    f32x4 s[4] = {};
    __builtin_amdgcn_s_setprio(1);
    #pragma unroll
    for (int ks = 0; ks < 2; ++ks) {
      int ch = ((ks * 4 + (lane >> 4)) ^ (lane & 7)) * 8;
      #pragma unroll
      for (int sj = 0; sj < 4; ++sj) {
        bf16x8 kf = *(const bf16x8*)(Ks + (sj * 16 + (lane & 15)) * DHEAD + ch);
        s[sj] = mfma16(qf[ks], kf, s[sj]);
      }
    }
    __builtin_amdgcn_s_setprio(0);
    #pragma unroll
    for (int sj = 0; sj < 4; ++sj)
      #pragma unroll
      for (int e = 0; e < 4; ++e)
        s[sj][e] = fmaf(s[sj][e], C2LOG, addf[sj]);

    float vmax[4];
    #pragma unroll
    for (int e = 0; e < 4; ++e) {
      float v = fmaxf(fmaxf(s[0][e], s[1][e]), fmaxf(s[2][e], s[3][e]));
      v = fmaxf(v, __shfl_xor(v, 1));
      v = fmaxf(v, __shfl_xor(v, 2));
      v = fmaxf(v, __shfl_xor(v, 4));
      v = fmaxf(v, __shfl_xor(v, 8));
      vmax[e] = v;
    }
    // defer-max: only rescale when some row grew past mi + 11 (2^11 P-headroom)
    bool need = false;
    #pragma unroll
    for (int e = 0; e < 4; ++e) need |= (vmax[e] > mi[e] + 11.0f);
    if (__any(need)) {
      #pragma unroll
      for (int e = 0; e < 4; ++e) {
        float mnew = fmaxf(mi[e], vmax[e]);
        float alpha = exp2f(mi[e] - mnew);
        mi[e] = mnew;
        li[e] *= alpha;
        #pragma unroll
        for (int dj = 0; dj < 4; ++dj)
          oacc[dj][e] *= alpha;
      }
    }
    #pragma unroll
    for (int e = 0; e < 4; ++e) {
      float sum = 0.f;
      #pragma unroll
      for (int sj = 0; sj < 4; ++sj) {
        float p = exp2f(s[sj][e] - mi[e]);
        s[sj][e] = p;
        sum += p;
      }
      li[e] += sum;
    }

    // P (D-layout) -> per-wave LDS -> A-layout fragments
    #pragma unroll
    for (int sj = 0; sj < 4; ++sj)
      #pragma unroll
      for (int e = 0; e < 4; ++e)
        Ps[wave][((lane >> 4) * 4 + e) * PS_LD + sj * 16 + (lane & 15)] = (__bf16)s[sj][e];
    bf16x8 pf[2];
    #pragma unroll
    for (int c = 0; c < 2; ++c)
      pf[c] = *(const bf16x8*)(&Ps[wave][(lane & 15) * PS_LD + c * 32 + (lane >> 4) * 8]);
    __builtin_amdgcn_s_setprio(1);
    #pragma unroll
    for (int dj = 0; dj < 4; ++dj) {
      #pragma unroll
      for (int c = 0; c < 2; ++c) {
        int ch = ((c * 4 + (lane >> 4)) ^ (lane & 7)) * 8;
        bf16x8 vf = *(const bf16x8*)(Vs + (dj * 16 + (lane & 15)) * DHEAD + ch);
        oacc[dj] = mfma16(pf[c], vf, oacc[dj]);
      }
    }
    __builtin_amdgcn_s_setprio(0);

    __builtin_amdgcn_s_barrier();           // all waves done reading buffers kt
    if (kt + 2 < nt) {
      __bf16* Kn = (kt & 1) ? K1 : K0;      // buffer (kt+2)&1 = just-consumed one
      __bf16* Vn = (kt & 1) ? V1 : V0;
      ASTAGE(kt + 2, Kn, Vn);
    }
  }

  // final cross-lane l reduction (once, instead of per tile)
  #pragma unroll
  for (int e = 0; e < 4; ++e) {
    float l = li[e];
    l += __shfl_xor(l, 1);
    l += __shfl_xor(l, 2);
    l += __shfl_xor(l, 4);
    l += __shfl_xor(l, 8);
    li[e] = l;
  }

  #pragma unroll
  for (int e = 0; e < 4; ++e) {
    int n = q0 + (lane >> 4) * 4 + e;
    if (n < SEQ) {
      float inv = 1.0f / li[e];
      #pragma unroll
      for (int dj = 0; dj < 4; ++dj)
        ob[((size_t)b * SEQ + n) * DIM + hh * DHEAD + dj * 16 + (lane & 15)] =
            (__bf16)(oacc[dj][e] * inv);
    }
  }
}

// ---------------- workspace layout (bytes) ----------------
static const size_t OFF_WTQKV = 0;                               // layer-0 slab (SLAB bytes)
static const size_t OFF_H     = SLAB;                            // 12160*512*2
static const size_t OFF_Q     = OFF_H  + 12451840;               // 128*760*64*2
static const size_t OFF_K     = OFF_Q  + 12451840;               // 128*768*64*2
static const size_t OFF_VT    = OFF_K  + 12582912;               // 128*64*768*2
static const size_t OFF_O     = OFF_VT + 12582912;               // 12160*512*2
static const size_t OFF_IDX   = OFF_O  + 12451840;               // 16*760*4
static const size_t OFF_VC    = OFF_IDX + 49152;                 // 16*4
static const size_t OFF_EXTRA = OFF_VC + 4096;                   // slabs for layers 1..5 (hoisted)
static const size_t NEED_HOIST = OFF_EXTRA + 5 * (size_t)SLAB;   // ~100.3 MB
static const size_t OFF_FF    = OFF_Q;  // ff aliases q/k/vt/o (dead by then)

extern "C" void kernel_launch(void* const* d_in, const int* in_sizes, int n_in,
                              void* d_out, int out_size, void* d_ws, size_t ws_size,
                              hipStream_t stream) {
  const float* x    = (const float*)d_in[0];
  const int*   vseq = (const int*)d_in[1];
  const float* ln1g = (const float*)d_in[3];
  const float* ln1b = (const float*)d_in[4];
  const float* wqkv = (const float*)d_in[5];
  const float* wout = (const float*)d_in[6];
  const float* bout = (const float*)d_in[7];
  const float* ln2g = (const float*)d_in[8];
  const float* ln2b = (const float*)d_in[9];
  const float* w1   = (const float*)d_in[10];
  const float* b1   = (const float*)d_in[11];
  const float* w2   = (const float*)d_in[12];
  const float* b2   = (const float*)d_in[13];

  float* xbuf = (float*)d_out;
  char* ws = (char*)d_ws;
  __bf16* hb     = (__bf16*)(ws + OFF_H);
  __bf16* qbuf   = (__bf16*)(ws + OFF_Q);
  __bf16* kbuf   = (__bf16*)(ws + OFF_K);
  __bf16* vtbuf  = (__bf16*)(ws + OFF_VT);
  __bf16* obuf   = (__bf16*)(ws + OFF_O);
  __bf16* ffbuf  = (__bf16*)(ws + OFF_FF);
  int* didx = (int*)(ws + OFF_IDX);
  int* vcnt = (int*)(ws + OFF_VC);

  bool hoist = (ws_size >= NEED_HOIST);

  scan_kernel<<<BATCH, 64, 0, stream>>>(vseq, didx, vcnt);

  if (hoist)
    wconv_all6_kernel<<<DEPTH * 3072, dim3(32, 8), 0, stream>>>(
        wqkv, wout, w1, w2, ws, OFF_EXTRA);

  for (int i = 0; i < DEPTH; ++i) {
    const float* xin = (i == 0) ? x : xbuf;

    char* slab = hoist
        ? (i == 0 ? ws : ws + OFF_EXTRA + (size_t)(i - 1) * SLAB)
        : ws;
    __bf16* wt_qkv = (__bf16*)(slab + 0);
    __bf16* wt_out = (__bf16*)(slab + 1572864);
    __bf16* wt_w1  = (__bf16*)(slab + 2097152);
    __bf16* wt_w2  = (__bf16*)(slab + 4194304);

    if (!hoist)
      wconv_all_kernel<<<3072, dim3(32, 8), 0, stream>>>(
          wqkv + (size_t)i * DIM * 1536, wout + (size_t)i * DIM * DIM,
          w1 + (size_t)i * DIM * MLP_D, w2 + (size_t)i * MLP_D * DIM, slab);

    ln_kernel<<<ROWS / 4, 256, 0, stream>>>(xin, ln1g + i * DIM, ln1b + i * DIM, hb);

    gemm_kernel<<<dim3(12, 95), 512, 0, stream>>>(
        hb, wt_qkv, ROWS, 1536, DIM, 3,
        nullptr, nullptr, nullptr, nullptr, qbuf, kbuf, vtbuf, didx);

    attn_kernel<<<dim3(6, BATCH * HEADS), 512, 0, stream>>>(
        qbuf, kbuf, vtbuf, vcnt, obuf);

    gemm_kernel<<<dim3(4, 95), 512, 0, stream>>>(
        obuf, wt_out, ROWS, DIM, DIM, 2,
        xbuf, nullptr, bout + i * DIM, xin, nullptr, nullptr, nullptr, nullptr);

    ln_kernel<<<ROWS / 4, 256, 0, stream>>>(xbuf, ln2g + i * DIM, ln2b + i * DIM, hb);

    gemm_kernel<<<dim3(16, 95), 512, 0, stream>>>(
        hb, wt_w1, ROWS, MLP_D, DIM, 1,
        nullptr, ffbuf, b1 + i * MLP_D, nullptr, nullptr, nullptr, nullptr, nullptr);

    gemm_kernel<<<dim3(4, 95), 512, 0, stream>>>(
        ffbuf, wt_w2, ROWS, DIM, MLP_D, 2,
        xbuf, nullptr, b2 + i * DIM, xbuf, nullptr, nullptr, nullptr, nullptr);
  }
}